// Round 1
// baseline (8248.640 us; speedup 1.0000x reference)
//
#include <hip/hip_runtime.h>
#include <cmath>

// Problem constants
//   B=2, S=2048, E=2048, H=16, D=128, M=B*S=4096, F=2E=4096
// Reference: q=x@Wq.T etc (NT gemm), causal softmax attention, FFN with
// tanh-approx GELU (jax.nn.gelu default approximate=True).

#define TQ 32

// ---------------- NT GEMM: C[m][n] = sum_k A[m][k] * Bm[n][k] ------------
// A: M x K row-major, Bm: N x K row-major, C: M x N row-major.
// 64x64 block tile, BK=16, 256 threads, 4x4 micro-tile per thread.
template <bool BIAS, bool GELU>
__global__ __launch_bounds__(256) void gemm_nt(const float* __restrict__ A,
                                               const float* __restrict__ Bm,
                                               const float* __restrict__ bias,
                                               float* __restrict__ C,
                                               int M, int N, int K) {
  __shared__ float As[64][17];
  __shared__ float Bs[64][17];
  const int tid = threadIdx.x;
  const int bm = blockIdx.y * 64;
  const int bn = blockIdx.x * 64;
  const int tx = tid & 15;   // 0..15
  const int ty = tid >> 4;   // 0..15
  const int lr = tid >> 4;   // load row base
  const int lc = tid & 15;   // load col (k)

  float acc[4][4] = {};

  for (int k0 = 0; k0 < K; k0 += 16) {
#pragma unroll
    for (int i = 0; i < 4; i++) {
      As[lr + 16 * i][lc] = A[(size_t)(bm + lr + 16 * i) * K + k0 + lc];
      Bs[lr + 16 * i][lc] = Bm[(size_t)(bn + lr + 16 * i) * K + k0 + lc];
    }
    __syncthreads();
#pragma unroll
    for (int kk = 0; kk < 16; kk++) {
      float a[4], b[4];
#pragma unroll
      for (int i = 0; i < 4; i++) a[i] = As[ty * 4 + i][kk];
#pragma unroll
      for (int j = 0; j < 4; j++) b[j] = Bs[tx * 4 + j][kk];
#pragma unroll
      for (int i = 0; i < 4; i++)
#pragma unroll
        for (int j = 0; j < 4; j++) acc[i][j] += a[i] * b[j];
    }
    __syncthreads();
  }

#pragma unroll
  for (int i = 0; i < 4; i++) {
    const int m = bm + ty * 4 + i;
#pragma unroll
    for (int j = 0; j < 4; j++) {
      const int n = bn + tx * 4 + j;
      float v = acc[i][j];
      if (BIAS) v += bias[n];
      if (GELU) {
        // jax.nn.gelu approximate=True (tanh approximation)
        const float x = v;
        const float inner = 0.7978845608028654f * (x + 0.044715f * x * x * x);
        v = 0.5f * x * (1.0f + tanhf(inner));
      }
      C[(size_t)m * N + n] = v;
    }
  }
}

// ---------------- Flash-style causal attention ---------------------------
// Q,K,V,O stored as (B*S, E) row-major; per head h the slice is cols
// [h*128, h*128+128). One block handles TQ=32 query rows of one (b,h).
__global__ __launch_bounds__(256) void attn_kernel(const float* __restrict__ Qb,
                                                   const float* __restrict__ Kb,
                                                   const float* __restrict__ Vb,
                                                   float* __restrict__ Ob) {
  const int qt = blockIdx.x;  // q-tile index
  const int h = blockIdx.y;
  const int b = blockIdx.z;
  const int q0 = qt * TQ;
  const int t = threadIdx.x;

  __shared__ float Qs[TQ][129];
  __shared__ float Ks[TQ][129];
  __shared__ float Vs[TQ][129];
  __shared__ float Ss[TQ][33];
  __shared__ float Ps[TQ][33];
  __shared__ float mrow[TQ], lrow[TQ], arow[TQ];

  const float scale = 0.08838834764831845f;  // 1/sqrt(128)

  const float* Qh = Qb + ((size_t)b * 2048 + q0) * 2048 + h * 128;
  const float* Kh = Kb + ((size_t)b * 2048) * 2048 + h * 128;
  const float* Vh = Vb + ((size_t)b * 2048) * 2048 + h * 128;

  // Load Q tile (scale folded in; mask is -inf so order vs scale is moot)
#pragma unroll
  for (int i = 0; i < 16; i++) {
    const int idx = t + i * 256;
    const int r = idx >> 7, d = idx & 127;
    Qs[r][d] = Qh[(size_t)r * 2048 + d] * scale;
  }
  if (t < TQ) {
    mrow[t] = -INFINITY;
    lrow[t] = 0.0f;
  }

  float o[16];
#pragma unroll
  for (int i = 0; i < 16; i++) o[i] = 0.0f;

  const int r_own = t >> 3;        // S row / O row this thread works on
  const int c4 = (t & 7) * 4;      // S cols base
  const int dbase = t & 7;         // O col = dbase + 8*i

  for (int kb = 0; kb <= qt; kb++) {
    const int k0 = kb * TQ;
    __syncthreads();  // previous iteration finished with Ks/Vs/Ps
#pragma unroll
    for (int i = 0; i < 16; i++) {
      const int idx = t + i * 256;
      const int r = idx >> 7, d = idx & 127;
      Ks[r][d] = Kh[(size_t)(k0 + r) * 2048 + d];
      Vs[r][d] = Vh[(size_t)(k0 + r) * 2048 + d];
    }
    __syncthreads();

    // S tile: each thread does 4 columns of one row
    float s[4];
#pragma unroll
    for (int j = 0; j < 4; j++) s[j] = 0.0f;
    for (int d = 0; d < 128; d++) {
      const float qv = Qs[r_own][d];
#pragma unroll
      for (int j = 0; j < 4; j++) s[j] += qv * Ks[c4 + j][d];
    }
    const bool diag = (kb == qt);
#pragma unroll
    for (int j = 0; j < 4; j++) {
      const int c = c4 + j;
      float sv = s[j];
      if (diag && (k0 + c > q0 + r_own)) sv = -INFINITY;
      Ss[r_own][c] = sv;
    }
    __syncthreads();

    // Online softmax, one thread per row
    if (t < TQ) {
      const float m_old = mrow[t];
      float mx = m_old;
      for (int c = 0; c < TQ; c++) mx = fmaxf(mx, Ss[t][c]);
      const float alpha = expf(m_old - mx);  // m_old=-inf -> 0
      float sum = 0.0f;
      for (int c = 0; c < TQ; c++) {
        const float p = expf(Ss[t][c] - mx);
        Ps[t][c] = p;
        sum += p;
      }
      mrow[t] = mx;
      lrow[t] = lrow[t] * alpha + sum;
      arow[t] = alpha;
    }
    __syncthreads();

    // O update: o[r_own][dbase + 8i]
    const float alpha = arow[r_own];
#pragma unroll
    for (int i = 0; i < 16; i++) o[i] *= alpha;
    for (int c = 0; c < TQ; c++) {
      const float p = Ps[r_own][c];
#pragma unroll
      for (int i = 0; i < 16; i++) o[i] += p * Vs[c][dbase + 8 * i];
    }
  }

  __syncthreads();
  const float inv = 1.0f / lrow[r_own];
  float* Oh = Ob + ((size_t)b * 2048 + q0) * 2048 + h * 128;
#pragma unroll
  for (int i = 0; i < 16; i++) {
    Oh[(size_t)r_own * 2048 + dbase + 8 * i] = o[i] * inv;
  }
}

// ---------------- launcher ----------------------------------------------
extern "C" void kernel_launch(void* const* d_in, const int* in_sizes, int n_in,
                              void* d_out, int out_size, void* d_ws,
                              size_t ws_size, hipStream_t stream) {
  const float* x = (const float*)d_in[0];
  const float* Wq = (const float*)d_in[1];
  const float* Wk = (const float*)d_in[2];
  const float* Wv = (const float*)d_in[3];
  const float* W1 = (const float*)d_in[4];
  const float* b1 = (const float*)d_in[5];
  const float* W2 = (const float*)d_in[6];
  const float* b2 = (const float*)d_in[7];
  float* out = (float*)d_out;

  const int M = 4096;  // B*S
  const int E = 2048;
  const int F = 4096;  // 2*E

  float* Q = (float*)d_ws;          // M*E floats
  float* K = Q + (size_t)M * E;     // M*E floats
  float* V = K + (size_t)M * E;     // M*E floats
  float* O = Q;                     // alias: safe (disjoint per-workgroup R/W)
  float* Hid = K;                   // alias over K+V: M*F floats

  dim3 blk(256);

  // QKV projections
  gemm_nt<false, false><<<dim3(E / 64, M / 64), blk, 0, stream>>>(x, Wq, nullptr, Q, M, E, E);
  gemm_nt<false, false><<<dim3(E / 64, M / 64), blk, 0, stream>>>(x, Wk, nullptr, K, M, E, E);
  gemm_nt<false, false><<<dim3(E / 64, M / 64), blk, 0, stream>>>(x, Wv, nullptr, V, M, E, E);

  // Attention
  attn_kernel<<<dim3(2048 / TQ, 16, 2), blk, 0, stream>>>(Q, K, V, O);

  // FFN
  gemm_nt<true, true><<<dim3(F / 64, M / 64), blk, 0, stream>>>(O, W1, b1, Hid, M, F, E);
  gemm_nt<true, false><<<dim3(E / 64, M / 64), blk, 0, stream>>>(Hid, W2, b2, out, M, E, F);
}

// Round 3
// 3995.728 us; speedup vs baseline: 2.0644x; 2.0644x over previous
//
#include <hip/hip_runtime.h>
#include <cmath>

// Problem: B=2, S=2048, E=2048, H=16, D=128, M=B*S=4096, F=2E=4096
// GEMMs via split-bf16 MFMA (x = hi + lo, 3-term product, fp32 accum ~ fp32
// precision). Attention still fp32 vector (next round).

#define TQ 32

typedef short short8 __attribute__((ext_vector_type(8)));
typedef short short4v __attribute__((ext_vector_type(4)));
typedef float float4v __attribute__((ext_vector_type(4)));

struct HL { short h, l; };

__device__ inline HL split2(float f) {
  unsigned u = __builtin_bit_cast(unsigned, f);
  HL r;
  r.h = (short)(u >> 16);                                  // truncated bf16 hi
  float hf = __builtin_bit_cast(float, u & 0xFFFF0000u);   // exact float(hi)
  float res = f - hf;                                      // exact residual
  r.l = (short)(__builtin_bit_cast(unsigned, res) >> 16);  // bf16 lo
  return r;
}

// ---------------- NT GEMM via split-bf16 MFMA ----------------------------
// C[m][n] = sum_k A[m][k]*Bm[n][k].  A: MxK, Bm: NxK, C: MxN (row-major).
// 128x128 tile, BK=32, 256 threads = 4 waves in 2x2; each wave 64x64 via
// 4x4 grid of 16x16x32 MFMAs, 3 split-terms each.
template <bool BIAS, bool GELU>
__global__ __launch_bounds__(256) void gemm_nt_mfma(
    const float* __restrict__ A, const float* __restrict__ Bm,
    const float* __restrict__ bias, float* __restrict__ C,
    int M, int N, int K) {
  // LDS tiles: 128 rows x 32 k, stride 40 shorts (80 B -> 2-way bank alias = free)
  __shared__ short Ah[128][40];
  __shared__ short Al[128][40];
  __shared__ short Bh[128][40];
  __shared__ short Bl[128][40];

  const int tid = threadIdx.x;
  const int wave = tid >> 6;
  const int lane = tid & 63;
  const int bm = blockIdx.y * 128;
  const int bn = blockIdx.x * 128;
  const int wm = (wave & 1) * 64;
  const int wn = (wave >> 1) * 64;
  const int l16 = lane & 15;
  const int quad = lane >> 4;

  float4v acc[4][4] = {};

  // staging map: idx = tid + r*256 (r=0..3) covers 128x32 tile as float4s:
  // row = idx>>3 (0..127), c4 = (idx&7)*4
  const int srow = tid >> 3;          // rows covered: srow + r*32
  const int sc4 = (tid & 7) * 4;

  float4v pa[4], pb[4];
#pragma unroll
  for (int r = 0; r < 4; r++) {
    const int row = srow + r * 32;
    pa[r] = *(const float4v*)&A[(size_t)(bm + row) * K + sc4];
    pb[r] = *(const float4v*)&Bm[(size_t)(bn + row) * K + sc4];
  }

  for (int k0 = 0; k0 < K; k0 += 32) {
    // convert + write staged chunk to LDS
#pragma unroll
    for (int r = 0; r < 4; r++) {
      const int row = srow + r * 32;
      short4v ah, al, bh, bl;
#pragma unroll
      for (int e = 0; e < 4; e++) {
        HL a = split2(pa[r][e]);
        HL b = split2(pb[r][e]);
        ah[e] = a.h; al[e] = a.l;
        bh[e] = b.h; bl[e] = b.l;
      }
      *(short4v*)&Ah[row][sc4] = ah;
      *(short4v*)&Al[row][sc4] = al;
      *(short4v*)&Bh[row][sc4] = bh;
      *(short4v*)&Bl[row][sc4] = bl;
    }
    __syncthreads();

    // prefetch next chunk's globals behind the MFMA phase
    if (k0 + 32 < K) {
#pragma unroll
      for (int r = 0; r < 4; r++) {
        const int row = srow + r * 32;
        pa[r] = *(const float4v*)&A[(size_t)(bm + row) * K + k0 + 32 + sc4];
        pb[r] = *(const float4v*)&Bm[(size_t)(bn + row) * K + k0 + 32 + sc4];
      }
    }

    // fragments: lane reads 8 contiguous k (16B) from its row
    short8 af_h[4], af_l[4], bf_h[4], bf_l[4];
#pragma unroll
    for (int i = 0; i < 4; i++) {
      af_h[i] = *(const short8*)&Ah[wm + i * 16 + l16][quad * 8];
      af_l[i] = *(const short8*)&Al[wm + i * 16 + l16][quad * 8];
      bf_h[i] = *(const short8*)&Bh[wn + i * 16 + l16][quad * 8];
      bf_l[i] = *(const short8*)&Bl[wn + i * 16 + l16][quad * 8];
    }

#pragma unroll
    for (int i = 0; i < 4; i++)
#pragma unroll
      for (int j = 0; j < 4; j++) {
        acc[i][j] = __builtin_amdgcn_mfma_f32_16x16x32_bf16(af_h[i], bf_h[j], acc[i][j], 0, 0, 0);
        acc[i][j] = __builtin_amdgcn_mfma_f32_16x16x32_bf16(af_h[i], bf_l[j], acc[i][j], 0, 0, 0);
        acc[i][j] = __builtin_amdgcn_mfma_f32_16x16x32_bf16(af_l[i], bf_h[j], acc[i][j], 0, 0, 0);
      }
    __syncthreads();
  }

  // epilogue: C/D layout col=lane&15, row=quad*4+reg
#pragma unroll
  for (int j = 0; j < 4; j++) {
    const int col = bn + wn + j * 16 + l16;
    const float bv = BIAS ? bias[col] : 0.0f;
#pragma unroll
    for (int i = 0; i < 4; i++) {
      const int rbase = bm + wm + i * 16 + quad * 4;
#pragma unroll
      for (int reg = 0; reg < 4; reg++) {
        float v = acc[i][j][reg] + bv;
        if (GELU) {
          const float x = v;
          const float inner = 0.7978845608028654f * (x + 0.044715f * x * x * x);
          v = 0.5f * x * (1.0f + tanhf(inner));
        }
        C[(size_t)(rbase + reg) * N + col] = v;
      }
    }
  }
}

// ---------------- Flash-style causal attention (fp32, unchanged) ---------
__global__ __launch_bounds__(256) void attn_kernel(const float* __restrict__ Qb,
                                                   const float* __restrict__ Kb,
                                                   const float* __restrict__ Vb,
                                                   float* __restrict__ Ob) {
  const int qt = blockIdx.x;
  const int h = blockIdx.y;
  const int b = blockIdx.z;
  const int q0 = qt * TQ;
  const int t = threadIdx.x;

  __shared__ float Qs[TQ][129];
  __shared__ float Ks[TQ][129];
  __shared__ float Vs[TQ][129];
  __shared__ float Ss[TQ][33];
  __shared__ float Ps[TQ][33];
  __shared__ float mrow[TQ], lrow[TQ], arow[TQ];

  const float scale = 0.08838834764831845f;  // 1/sqrt(128)

  const float* Qh = Qb + ((size_t)b * 2048 + q0) * 2048 + h * 128;
  const float* Kh = Kb + ((size_t)b * 2048) * 2048 + h * 128;
  const float* Vh = Vb + ((size_t)b * 2048) * 2048 + h * 128;

#pragma unroll
  for (int i = 0; i < 16; i++) {
    const int idx = t + i * 256;
    const int r = idx >> 7, d = idx & 127;
    Qs[r][d] = Qh[(size_t)r * 2048 + d] * scale;
  }
  if (t < TQ) {
    mrow[t] = -INFINITY;
    lrow[t] = 0.0f;
  }

  float o[16];
#pragma unroll
  for (int i = 0; i < 16; i++) o[i] = 0.0f;

  const int r_own = t >> 3;
  const int c4 = (t & 7) * 4;
  const int dbase = t & 7;

  for (int kb = 0; kb <= qt; kb++) {
    const int k0 = kb * TQ;
    __syncthreads();
#pragma unroll
    for (int i = 0; i < 16; i++) {
      const int idx = t + i * 256;
      const int r = idx >> 7, d = idx & 127;
      Ks[r][d] = Kh[(size_t)(k0 + r) * 2048 + d];
      Vs[r][d] = Vh[(size_t)(k0 + r) * 2048 + d];
    }
    __syncthreads();

    float s[4];
#pragma unroll
    for (int j = 0; j < 4; j++) s[j] = 0.0f;
    for (int d = 0; d < 128; d++) {
      const float qv = Qs[r_own][d];
#pragma unroll
      for (int j = 0; j < 4; j++) s[j] += qv * Ks[c4 + j][d];
    }
    const bool diag = (kb == qt);
#pragma unroll
    for (int j = 0; j < 4; j++) {
      const int c = c4 + j;
      float sv = s[j];
      if (diag && (k0 + c > q0 + r_own)) sv = -INFINITY;
      Ss[r_own][c] = sv;
    }
    __syncthreads();

    if (t < TQ) {
      const float m_old = mrow[t];
      float mx = m_old;
      for (int c = 0; c < TQ; c++) mx = fmaxf(mx, Ss[t][c]);
      const float alpha = expf(m_old - mx);
      float sum = 0.0f;
      for (int c = 0; c < TQ; c++) {
        const float p = expf(Ss[t][c] - mx);
        Ps[t][c] = p;
        sum += p;
      }
      mrow[t] = mx;
      lrow[t] = lrow[t] * alpha + sum;
      arow[t] = alpha;
    }
    __syncthreads();

    const float alpha = arow[r_own];
#pragma unroll
    for (int i = 0; i < 16; i++) o[i] *= alpha;
    for (int c = 0; c < TQ; c++) {
      const float p = Ps[r_own][c];
#pragma unroll
      for (int i = 0; i < 16; i++) o[i] += p * Vs[c][dbase + 8 * i];
    }
  }

  __syncthreads();
  const float inv = 1.0f / lrow[r_own];
  float* Oh = Ob + ((size_t)b * 2048 + q0) * 2048 + h * 128;
#pragma unroll
  for (int i = 0; i < 16; i++) {
    Oh[(size_t)r_own * 2048 + dbase + 8 * i] = o[i] * inv;
  }
}

// ---------------- launcher ----------------------------------------------
extern "C" void kernel_launch(void* const* d_in, const int* in_sizes, int n_in,
                              void* d_out, int out_size, void* d_ws,
                              size_t ws_size, hipStream_t stream) {
  const float* x = (const float*)d_in[0];
  const float* Wq = (const float*)d_in[1];
  const float* Wk = (const float*)d_in[2];
  const float* Wv = (const float*)d_in[3];
  const float* W1 = (const float*)d_in[4];
  const float* b1 = (const float*)d_in[5];
  const float* W2 = (const float*)d_in[6];
  const float* b2 = (const float*)d_in[7];
  float* out = (float*)d_out;

  const int M = 4096;
  const int E = 2048;
  const int F = 4096;

  float* Q = (float*)d_ws;
  float* K = Q + (size_t)M * E;
  float* V = K + (size_t)M * E;
  float* O = Q;     // alias: attention reads/writes disjoint per-workgroup slices
  float* Hid = K;   // alias over K+V after attention

  dim3 blk(256);

  gemm_nt_mfma<false, false><<<dim3(E / 128, M / 128), blk, 0, stream>>>(x, Wq, nullptr, Q, M, E, E);
  gemm_nt_mfma<false, false><<<dim3(E / 128, M / 128), blk, 0, stream>>>(x, Wk, nullptr, K, M, E, E);
  gemm_nt_mfma<false, false><<<dim3(E / 128, M / 128), blk, 0, stream>>>(x, Wv, nullptr, V, M, E, E);

  attn_kernel<<<dim3(2048 / TQ, 16, 2), blk, 0, stream>>>(Q, K, V, O);

  gemm_nt_mfma<true, true><<<dim3(F / 128, M / 128), blk, 0, stream>>>(O, W1, b1, Hid, M, F, E);
  gemm_nt_mfma<true, false><<<dim3(E / 128, M / 128), blk, 0, stream>>>(Hid, W2, b2, out, M, E, F);
}

// Round 4
// 1127.314 us; speedup vs baseline: 7.3171x; 3.5445x over previous
//
#include <hip/hip_runtime.h>
#include <cmath>

// B=2, S=2048, E=2048, H=16, D=128, M=B*S=4096, F=2E=4096
// All matmuls via split-bf16 MFMA (x = hi + lo, 3-term product, fp32 accum).
// QKV stored as packed (lo<<16)|hi bf16 pairs; V stored transposed for PV.

typedef short short8 __attribute__((ext_vector_type(8)));
typedef short short4v __attribute__((ext_vector_type(4)));
typedef float float4v __attribute__((ext_vector_type(4)));
typedef int int4v __attribute__((ext_vector_type(4)));

struct HL { short h, l; };

__device__ inline HL split2(float f) {
  unsigned u = __builtin_bit_cast(unsigned, f);
  HL r;
  r.h = (short)(u >> 16);                                  // truncated bf16 hi
  float hf = __builtin_bit_cast(float, u & 0xFFFF0000u);   // exact float(hi)
  float res = f - hf;                                      // exact residual
  r.l = (short)(__builtin_bit_cast(unsigned, res) >> 16);  // bf16 lo
  return r;
}

__device__ inline int packHL(float f) {
  HL t = split2(f);
  return (int)(((unsigned)(unsigned short)t.l << 16) | (unsigned short)t.h);
}

__device__ inline void unpack8(const int4v& a, const int4v& b, short8& hi, short8& lo) {
#pragma unroll
  for (int j = 0; j < 4; j++) {
    hi[j] = (short)(a[j] & 0xffff);
    lo[j] = (short)(((unsigned)a[j]) >> 16);
  }
#pragma unroll
  for (int j = 0; j < 4; j++) {
    hi[4 + j] = (short)(b[j] & 0xffff);
    lo[4 + j] = (short)(((unsigned)b[j]) >> 16);
  }
}

// ---------------- NT GEMM via split-bf16 MFMA ----------------------------
// C[m][n] = sum_k A[m][k]*Bm[n][k].  Modes: 0=f32, 1=f32+bias+gelu,
// 2=packed HL int, 3=packed HL int transposed per-batch (for V).
template <int MODE, bool BIAS>
__global__ __launch_bounds__(256) void gemm_nt_mfma(
    const float* __restrict__ A, const float* __restrict__ Bm,
    const float* __restrict__ bias, void* __restrict__ Cout,
    int M, int N, int K, float oscale) {
  __shared__ short Ah[128][40];
  __shared__ short Al[128][40];
  __shared__ short Bh[128][40];
  __shared__ short Bl[128][40];

  const int tid = threadIdx.x;
  const int wave = tid >> 6;
  const int lane = tid & 63;
  const int bm = blockIdx.y * 128;
  const int bn = blockIdx.x * 128;
  const int wm = (wave & 1) * 64;
  const int wn = (wave >> 1) * 64;
  const int l16 = lane & 15;
  const int quad = lane >> 4;

  float4v acc[4][4] = {};

  const int srow = tid >> 3;
  const int sc4 = (tid & 7) * 4;

  float4v pa[4], pb[4];
#pragma unroll
  for (int r = 0; r < 4; r++) {
    const int row = srow + r * 32;
    pa[r] = *(const float4v*)&A[(size_t)(bm + row) * K + sc4];
    pb[r] = *(const float4v*)&Bm[(size_t)(bn + row) * K + sc4];
  }

  for (int k0 = 0; k0 < K; k0 += 32) {
#pragma unroll
    for (int r = 0; r < 4; r++) {
      const int row = srow + r * 32;
      short4v ah, al, bh, bl;
#pragma unroll
      for (int e = 0; e < 4; e++) {
        HL a = split2(pa[r][e]);
        HL b = split2(pb[r][e]);
        ah[e] = a.h; al[e] = a.l;
        bh[e] = b.h; bl[e] = b.l;
      }
      *(short4v*)&Ah[row][sc4] = ah;
      *(short4v*)&Al[row][sc4] = al;
      *(short4v*)&Bh[row][sc4] = bh;
      *(short4v*)&Bl[row][sc4] = bl;
    }
    __syncthreads();

    if (k0 + 32 < K) {
#pragma unroll
      for (int r = 0; r < 4; r++) {
        const int row = srow + r * 32;
        pa[r] = *(const float4v*)&A[(size_t)(bm + row) * K + k0 + 32 + sc4];
        pb[r] = *(const float4v*)&Bm[(size_t)(bn + row) * K + k0 + 32 + sc4];
      }
    }

    short8 af_h[4], af_l[4], bf_h[4], bf_l[4];
#pragma unroll
    for (int i = 0; i < 4; i++) {
      af_h[i] = *(const short8*)&Ah[wm + i * 16 + l16][quad * 8];
      af_l[i] = *(const short8*)&Al[wm + i * 16 + l16][quad * 8];
      bf_h[i] = *(const short8*)&Bh[wn + i * 16 + l16][quad * 8];
      bf_l[i] = *(const short8*)&Bl[wn + i * 16 + l16][quad * 8];
    }

#pragma unroll
    for (int i = 0; i < 4; i++)
#pragma unroll
      for (int j = 0; j < 4; j++) {
        acc[i][j] = __builtin_amdgcn_mfma_f32_16x16x32_bf16(af_h[i], bf_h[j], acc[i][j], 0, 0, 0);
        acc[i][j] = __builtin_amdgcn_mfma_f32_16x16x32_bf16(af_h[i], bf_l[j], acc[i][j], 0, 0, 0);
        acc[i][j] = __builtin_amdgcn_mfma_f32_16x16x32_bf16(af_l[i], bf_h[j], acc[i][j], 0, 0, 0);
      }
    __syncthreads();
  }

  // epilogue: C/D layout col=lane&15, row=quad*4+reg
#pragma unroll
  for (int j = 0; j < 4; j++) {
    const int col = bn + wn + j * 16 + l16;
    const float bv = BIAS ? bias[col] : 0.0f;
#pragma unroll
    for (int i = 0; i < 4; i++) {
      const int rbase = bm + wm + i * 16 + quad * 4;
#pragma unroll
      for (int reg = 0; reg < 4; reg++) {
        const int m = rbase + reg;
        float v = acc[i][j][reg] + bv;
        if (MODE == 1) {
          const float x = v;
          const float inner = 0.7978845608028654f * (x + 0.044715f * x * x * x);
          v = 0.5f * x * (1.0f + tanhf(inner));
        }
        if (MODE <= 1) {
          ((float*)Cout)[(size_t)m * N + col] = v;
        } else if (MODE == 2) {
          ((int*)Cout)[(size_t)m * N + col] = packHL(v * oscale);
        } else {  // MODE == 3: V^T per batch: [b][col][s]
          ((int*)Cout)[((size_t)(m >> 11) << 22) + ((size_t)col << 11) + (m & 2047)] = packHL(v);
        }
      }
    }
  }
}

// ---------------- MFMA flash attention -----------------------------------
// One block per (b, h, 128-row q-tile). 4 waves x 32 q-rows. 32-key tiles.
// Qp/Kp packed (M x E ints), Vtp packed transposed ([b][d 2048][s 2048]).
// Q pre-scaled by log2(e)/sqrt(D) -> softmax in exp2 domain.
__global__ __launch_bounds__(256, 2) void attn_mfma(
    const int* __restrict__ Qp, const int* __restrict__ Kp,
    const int* __restrict__ Vtp, float* __restrict__ Ob) {
  __shared__ int Ksh[32][132];     // [key][d]
  __shared__ int Vsh[128][36];     // [d][key]
  __shared__ int Psh[4][32][36];   // per-wave P: [qrow][key]

  const int b = blockIdx.z;
  int qt = blockIdx.x;
  if (b) qt = gridDim.x - 1 - qt;  // heavy/light pairing across CUs
  const int h = blockIdx.y;
  const int tid = threadIdx.x;
  const int wave = tid >> 6, lane = tid & 63;
  const int l16 = lane & 15, quad = lane >> 4;
  const int q0 = qt * 128;
  const int wq0 = q0 + wave * 32;

  // ---- Q fragments (A-layout), kept in registers all loop ----
  short8 qh[2][4], ql[2][4];
#pragma unroll
  for (int rb = 0; rb < 2; rb++)
#pragma unroll
    for (int kc = 0; kc < 4; kc++) {
      const int* src = Qp + ((size_t)(b * 2048 + wq0 + rb * 16 + l16)) * 2048 +
                       h * 128 + kc * 32 + quad * 8;
      int4v u0 = *(const int4v*)src;
      int4v u1 = *(const int4v*)(src + 4);
      unpack8(u0, u1, qh[rb][kc], ql[rb][kc]);
    }

  // staging maps
  const int kkey = tid >> 3;          // 0..31
  const int kd = (tid & 7) * 16;      // 0..112
  const int vd = tid >> 1;            // 0..127
  const int vkey = (tid & 1) * 16;    // 0/16

  int4v kpre[4], vpre[4];
  {
    const int* p = Kp + ((size_t)(b * 2048) + kkey) * 2048 + h * 128 + kd;
#pragma unroll
    for (int i = 0; i < 4; i++) kpre[i] = *(const int4v*)(p + 4 * i);
    const int* pv = Vtp + ((size_t)b << 22) + (size_t)(h * 128 + vd) * 2048 + vkey;
#pragma unroll
    for (int i = 0; i < 4; i++) vpre[i] = *(const int4v*)(pv + 4 * i);
  }

  float4v o[2][8] = {};
  float4v mrow[2], lrow[2];
#pragma unroll
  for (int rb = 0; rb < 2; rb++)
#pragma unroll
    for (int e = 0; e < 4; e++) { mrow[rb][e] = -INFINITY; lrow[rb][e] = 0.0f; }

  const int nkb = qt * 4 + 4;
  for (int kb = 0; kb < nkb; kb++) {
    const int k0 = kb * 32;
    __syncthreads();
#pragma unroll
    for (int i = 0; i < 4; i++) *(int4v*)&Ksh[kkey][kd + 4 * i] = kpre[i];
#pragma unroll
    for (int i = 0; i < 4; i++) *(int4v*)&Vsh[vd][vkey + 4 * i] = vpre[i];
    __syncthreads();

    if (kb + 1 < nkb) {
      const int k1 = k0 + 32;
      const int* p = Kp + ((size_t)(b * 2048) + k1 + kkey) * 2048 + h * 128 + kd;
#pragma unroll
      for (int i = 0; i < 4; i++) kpre[i] = *(const int4v*)(p + 4 * i);
      const int* pv = Vtp + ((size_t)b << 22) + (size_t)(h * 128 + vd) * 2048 + k1 + vkey;
#pragma unroll
      for (int i = 0; i < 4; i++) vpre[i] = *(const int4v*)(pv + 4 * i);
    }

    if (k0 <= wq0 + 31) {
      // ---- S = Q K^T ----
      float4v s[2][2] = {};
#pragma unroll
      for (int kc = 0; kc < 4; kc++) {
        short8 kh[2], kl[2];
#pragma unroll
        for (int cb = 0; cb < 2; cb++) {
          int4v u0 = *(const int4v*)&Ksh[cb * 16 + l16][kc * 32 + quad * 8];
          int4v u1 = *(const int4v*)&Ksh[cb * 16 + l16][kc * 32 + quad * 8 + 4];
          unpack8(u0, u1, kh[cb], kl[cb]);
        }
#pragma unroll
        for (int rb = 0; rb < 2; rb++)
#pragma unroll
          for (int cb = 0; cb < 2; cb++) {
            s[rb][cb] = __builtin_amdgcn_mfma_f32_16x16x32_bf16(qh[rb][kc], kh[cb], s[rb][cb], 0, 0, 0);
            s[rb][cb] = __builtin_amdgcn_mfma_f32_16x16x32_bf16(qh[rb][kc], kl[cb], s[rb][cb], 0, 0, 0);
            s[rb][cb] = __builtin_amdgcn_mfma_f32_16x16x32_bf16(ql[rb][kc], kh[cb], s[rb][cb], 0, 0, 0);
          }
      }
      // ---- causal mask (diag band only) ----
      if (k0 + 31 > wq0) {
#pragma unroll
        for (int rb = 0; rb < 2; rb++)
#pragma unroll
          for (int cb = 0; cb < 2; cb++)
#pragma unroll
            for (int reg = 0; reg < 4; reg++) {
              const int key = k0 + cb * 16 + l16;
              const int row = wq0 + rb * 16 + quad * 4 + reg;
              if (key > row) s[rb][cb][reg] = -INFINITY;
            }
      }
      // ---- online softmax (exp2 domain) ----
#pragma unroll
      for (int rb = 0; rb < 2; rb++) {
        float4v mt;
#pragma unroll
        for (int e = 0; e < 4; e++) mt[e] = fmaxf(s[rb][0][e], s[rb][1][e]);
#pragma unroll
        for (int msk = 1; msk <= 8; msk <<= 1)
#pragma unroll
          for (int e = 0; e < 4; e++) mt[e] = fmaxf(mt[e], __shfl_xor(mt[e], msk, 64));
        float4v al;
#pragma unroll
        for (int e = 0; e < 4; e++) {
          const float mn = fmaxf(mrow[rb][e], mt[e]);
          al[e] = exp2f(mrow[rb][e] - mn);
          mrow[rb][e] = mn;
        }
        float4v rs;
#pragma unroll
        for (int e = 0; e < 4; e++) {
          s[rb][0][e] = exp2f(s[rb][0][e] - mrow[rb][e]);
          s[rb][1][e] = exp2f(s[rb][1][e] - mrow[rb][e]);
          rs[e] = s[rb][0][e] + s[rb][1][e];
        }
#pragma unroll
        for (int msk = 1; msk <= 8; msk <<= 1)
#pragma unroll
          for (int e = 0; e < 4; e++) rs[e] += __shfl_xor(rs[e], msk, 64);
#pragma unroll
        for (int e = 0; e < 4; e++) lrow[rb][e] = lrow[rb][e] * al[e] + rs[e];
#pragma unroll
        for (int cd = 0; cd < 8; cd++)
#pragma unroll
          for (int e = 0; e < 4; e++) o[rb][cd][e] *= al[e];
        // P -> LDS (C-layout write, packed split)
#pragma unroll
        for (int cb = 0; cb < 2; cb++)
#pragma unroll
          for (int reg = 0; reg < 4; reg++)
            Psh[wave][rb * 16 + quad * 4 + reg][cb * 16 + l16] = packHL(s[rb][cb][reg]);
      }
      // ---- P A-frags, then O += P V ----
      short8 ph[2], pl[2];
#pragma unroll
      for (int rb = 0; rb < 2; rb++) {
        int4v u0 = *(const int4v*)&Psh[wave][rb * 16 + l16][quad * 8];
        int4v u1 = *(const int4v*)&Psh[wave][rb * 16 + l16][quad * 8 + 4];
        unpack8(u0, u1, ph[rb], pl[rb]);
      }
#pragma unroll
      for (int cd = 0; cd < 8; cd++) {
        int4v u0 = *(const int4v*)&Vsh[cd * 16 + l16][quad * 8];
        int4v u1 = *(const int4v*)&Vsh[cd * 16 + l16][quad * 8 + 4];
        short8 vh, vl;
        unpack8(u0, u1, vh, vl);
#pragma unroll
        for (int rb = 0; rb < 2; rb++) {
          o[rb][cd] = __builtin_amdgcn_mfma_f32_16x16x32_bf16(ph[rb], vh, o[rb][cd], 0, 0, 0);
          o[rb][cd] = __builtin_amdgcn_mfma_f32_16x16x32_bf16(ph[rb], vl, o[rb][cd], 0, 0, 0);
          o[rb][cd] = __builtin_amdgcn_mfma_f32_16x16x32_bf16(pl[rb], vh, o[rb][cd], 0, 0, 0);
        }
      }
    }
  }

  // ---- finalize: O /= l, write fp32 ----
#pragma unroll
  for (int rb = 0; rb < 2; rb++) {
    float4v inv;
#pragma unroll
    for (int e = 0; e < 4; e++) inv[e] = 1.0f / lrow[rb][e];
#pragma unroll
    for (int cd = 0; cd < 8; cd++)
#pragma unroll
      for (int reg = 0; reg < 4; reg++)
        Ob[((size_t)(b * 2048 + wq0 + rb * 16 + quad * 4 + reg)) * 2048 +
           h * 128 + cd * 16 + l16] = o[rb][cd][reg] * inv[reg];
  }
}

// ---------------- launcher ----------------------------------------------
extern "C" void kernel_launch(void* const* d_in, const int* in_sizes, int n_in,
                              void* d_out, int out_size, void* d_ws,
                              size_t ws_size, hipStream_t stream) {
  const float* x = (const float*)d_in[0];
  const float* Wq = (const float*)d_in[1];
  const float* Wk = (const float*)d_in[2];
  const float* Wv = (const float*)d_in[3];
  const float* W1 = (const float*)d_in[4];
  const float* b1 = (const float*)d_in[5];
  const float* W2 = (const float*)d_in[6];
  const float* b2 = (const float*)d_in[7];
  float* out = (float*)d_out;

  const int M = 4096, E = 2048, F = 4096;

  int* Qp = (int*)d_ws;                 // M*E ints (packed)
  int* Kp = Qp + (size_t)M * E;         // M*E ints
  int* Vtp = Kp + (size_t)M * E;        // M*E ints, transposed per batch
  float* O = (float*)Qp;                // alias: per-block disjoint R/W
  float* Hid = (float*)Kp;              // alias over Kp+Vtp after attention

  // log2(e)/sqrt(128): softmax done in exp2 domain
  const float qscale = 1.4426950408889634f * 0.08838834764831845f;

  dim3 blk(256);
  gemm_nt_mfma<2, false><<<dim3(E / 128, M / 128), blk, 0, stream>>>(x, Wq, nullptr, Qp, M, E, E, qscale);
  gemm_nt_mfma<2, false><<<dim3(E / 128, M / 128), blk, 0, stream>>>(x, Wk, nullptr, Kp, M, E, E, 1.0f);
  gemm_nt_mfma<3, false><<<dim3(E / 128, M / 128), blk, 0, stream>>>(x, Wv, nullptr, Vtp, M, E, E, 1.0f);

  attn_mfma<<<dim3(16, 16, 2), blk, 0, stream>>>(Qp, Kp, Vtp, O);

  gemm_nt_mfma<1, true><<<dim3(F / 128, M / 128), blk, 0, stream>>>(O, W1, b1, Hid, M, F, E, 1.0f);
  gemm_nt_mfma<0, true><<<dim3(E / 128, M / 128), blk, 0, stream>>>(Hid, W2, b2, out, M, E, F, 1.0f);
}

// Round 5
// 733.053 us; speedup vs baseline: 11.2524x; 1.5378x over previous
//
#include <hip/hip_runtime.h>
#include <cmath>

// B=2, S=2048, E=2048, H=16, D=128, M=B*S=4096, F=2E=4096
// Everything single-fp16 MFMA with fp32 accumulation (error ~2e-4, well under
// observed baseline absmax 0.0039-0.0078). GEMMs use the m97 structure:
// global_load_lds width=16 staging, 128x128 tile, BK=32, 16 MFMA/wave-chunk.

typedef _Float16 half8 __attribute__((ext_vector_type(8)));
typedef _Float16 half4v __attribute__((ext_vector_type(4)));
typedef float float4v __attribute__((ext_vector_type(4)));

__device__ inline void load_lds16(const _Float16* g, _Float16* l) {
  __builtin_amdgcn_global_load_lds(
      (const __attribute__((address_space(1))) void*)g,
      (__attribute__((address_space(3))) void*)l, 16, 0, 0);
}

// ---------------- fp32 -> fp16 convert (up to 4 arrays per launch) -------
__global__ void cvt_kernel(const float* __restrict__ s0, const float* __restrict__ s1,
                           const float* __restrict__ s2, const float* __restrict__ s3,
                           _Float16* d0, _Float16* d1, _Float16* d2, _Float16* d3,
                           int n0, int n1, int n2, int n3, float sc1) {
  const float* s;
  _Float16* d;
  int n;
  float sc = 1.0f;
  switch (blockIdx.y) {
    case 0: s = s0; d = d0; n = n0; break;
    case 1: s = s1; d = d1; n = n1; sc = sc1; break;
    case 2: s = s2; d = d2; n = n2; break;
    default: s = s3; d = d3; n = n3; break;
  }
  const int step = gridDim.x * 256 * 4;
  for (int i = (blockIdx.x * 256 + threadIdx.x) * 4; i < n; i += step) {
    float4v v = *(const float4v*)&s[i];
    half4v h;
#pragma unroll
    for (int e = 0; e < 4; e++) h[e] = (_Float16)(v[e] * sc);
    *(half4v*)&d[i] = h;
  }
}

// ---------------- shared GEMM mainloop (m97 structure) -------------------
// C[m][n] = sum_k A[m][k]*B[n][k], A: MxK half, B: NxK half. 128x128 tile,
// BK=32, 256 threads = 4 waves (2x2), each wave 64x64 via 4x4 16x16x32 MFMAs.
__device__ inline void gemm_core(const _Float16* __restrict__ A,
                                 const _Float16* __restrict__ B, int K, int bm,
                                 int bn, _Float16* As, _Float16* Bs,
                                 float4v acc[4][4]) {
  const int tid = threadIdx.x;
  const int wave = tid >> 6, lane = tid & 63;
  const int l16 = lane & 15, quad = lane >> 4;
  const int wm = (wave & 1) * 64, wn = (wave >> 1) * 64;
  const int r0 = tid >> 2, c0 = (tid & 3) * 8;   // staging: row, k-offset
  const int lds0 = (wave * 64) * 8;              // wave-uniform LDS base, chunk 0
  const int lds1 = (256 + wave * 64) * 8;        // chunk 1

  for (int k0 = 0; k0 < K; k0 += 32) {
    load_lds16(&A[(size_t)(bm + r0) * K + k0 + c0], &As[lds0]);
    load_lds16(&A[(size_t)(bm + 64 + r0) * K + k0 + c0], &As[lds1]);
    load_lds16(&B[(size_t)(bn + r0) * K + k0 + c0], &Bs[lds0]);
    load_lds16(&B[(size_t)(bn + 64 + r0) * K + k0 + c0], &Bs[lds1]);
    __syncthreads();

    half8 af[4], bf[4];
#pragma unroll
    for (int i = 0; i < 4; i++)
      af[i] = *(const half8*)&As[(wm + i * 16 + l16) * 32 + quad * 8];
#pragma unroll
    for (int j = 0; j < 4; j++)
      bf[j] = *(const half8*)&Bs[(wn + j * 16 + l16) * 32 + quad * 8];

#pragma unroll
    for (int i = 0; i < 4; i++)
#pragma unroll
      for (int j = 0; j < 4; j++)
        acc[i][j] = __builtin_amdgcn_mfma_f32_16x16x32_f16(af[i], bf[j], acc[i][j], 0, 0, 0);
    __syncthreads();
  }
}

// ---------------- QKV: one launch, z = 0(Q)/1(K)/2(V transposed) ---------
__global__ __launch_bounds__(256, 3) void gemm_qkv(
    const _Float16* __restrict__ xh, const _Float16* __restrict__ Wq,
    const _Float16* __restrict__ Wk, const _Float16* __restrict__ Wv,
    _Float16* __restrict__ Qh, _Float16* __restrict__ Kh,
    _Float16* __restrict__ Vt) {
  __shared__ __align__(16) _Float16 As[4096];
  __shared__ __align__(16) _Float16 Bs[4096];
  const int z = blockIdx.z;
  const _Float16* B = (z == 0) ? Wq : (z == 1 ? Wk : Wv);
  const int bm = blockIdx.y * 128, bn = blockIdx.x * 128;
  float4v acc[4][4] = {};
  gemm_core(xh, B, 2048, bm, bn, As, Bs, acc);

  const int tid = threadIdx.x;
  const int wave = tid >> 6, lane = tid & 63;
  const int l16 = lane & 15, quad = lane >> 4;
  const int wm = (wave & 1) * 64, wn = (wave >> 1) * 64;
  _Float16* outRM = z ? Kh : Qh;
#pragma unroll
  for (int j = 0; j < 4; j++) {
    const int col = bn + wn + j * 16 + l16;
#pragma unroll
    for (int i = 0; i < 4; i++) {
      const int rbase = bm + wm + i * 16 + quad * 4;
#pragma unroll
      for (int reg = 0; reg < 4; reg++) {
        const int m = rbase + reg;
        const _Float16 hv = (_Float16)acc[i][j][reg];
        if (z == 2)
          Vt[((size_t)(m >> 11) << 22) + ((size_t)col << 11) + (m & 2047)] = hv;
        else
          outRM[(size_t)m * 2048 + col] = hv;
      }
    }
  }
}

// ---------------- FFN GEMMs ----------------------------------------------
template <bool GELU>
__global__ __launch_bounds__(256, 3) void gemm_ffn(
    const _Float16* __restrict__ A, const _Float16* __restrict__ B,
    const float* __restrict__ bias, void* __restrict__ out, int M, int N,
    int K) {
  __shared__ __align__(16) _Float16 As[4096];
  __shared__ __align__(16) _Float16 Bs[4096];
  const int bm = blockIdx.y * 128, bn = blockIdx.x * 128;
  float4v acc[4][4] = {};
  gemm_core(A, B, K, bm, bn, As, Bs, acc);

  const int tid = threadIdx.x;
  const int wave = tid >> 6, lane = tid & 63;
  const int l16 = lane & 15, quad = lane >> 4;
  const int wm = (wave & 1) * 64, wn = (wave >> 1) * 64;
#pragma unroll
  for (int j = 0; j < 4; j++) {
    const int col = bn + wn + j * 16 + l16;
    const float bv = bias[col];
#pragma unroll
    for (int i = 0; i < 4; i++) {
      const int rbase = bm + wm + i * 16 + quad * 4;
#pragma unroll
      for (int reg = 0; reg < 4; reg++) {
        const int m = rbase + reg;
        float v = acc[i][j][reg] + bv;
        if (GELU) {
          const float x = v;
          const float inner = 0.7978845608028654f * (x + 0.044715f * x * x * x);
          v = 0.5f * x * (1.0f + tanhf(inner));
          ((_Float16*)out)[(size_t)m * N + col] = (_Float16)v;
        } else {
          ((float*)out)[(size_t)m * N + col] = v;
        }
      }
    }
  }
}

// ---------------- fp16 MFMA flash attention ------------------------------
// One block per (b, h, 128-row q-tile). 4 waves x 32 q-rows, 32-key tiles.
// Qh pre-scaled by log2(e)/sqrt(D) (folded into Wq) -> softmax in exp2.
// LDS strides chosen so b128 reads tile all 32 banks (full BW).
__global__ __launch_bounds__(256, 3) void attn_mfma(
    const _Float16* __restrict__ Qh, const _Float16* __restrict__ Kh,
    const _Float16* __restrict__ Vt, _Float16* __restrict__ Oh) {
  __shared__ __align__(16) _Float16 Ksh[32][136];   // [key][d]
  __shared__ __align__(16) _Float16 Vsh[128][40];   // [d][key]
  __shared__ __align__(16) _Float16 Psh[4][32][40]; // per-wave [qrow][key]

  const int b = blockIdx.z;
  int qt = blockIdx.x;
  if (b) qt = gridDim.x - 1 - qt;  // heavy/light pairing across CUs
  const int h = blockIdx.y;
  const int tid = threadIdx.x;
  const int wave = tid >> 6, lane = tid & 63;
  const int l16 = lane & 15, quad = lane >> 4;
  const int q0 = qt * 128;
  const int wq0 = q0 + wave * 32;

  // Q fragments (A-layout), registers for whole loop
  half8 qf[2][4];
#pragma unroll
  for (int rb = 0; rb < 2; rb++)
#pragma unroll
    for (int kc = 0; kc < 4; kc++)
      qf[rb][kc] = *(const half8*)(Qh +
          (size_t)(b * 2048 + wq0 + rb * 16 + l16) * 2048 + h * 128 +
          kc * 32 + quad * 8);

  const int kkey = tid >> 3, kd = (tid & 7) * 16;
  const int vd = tid >> 1, vkey = (tid & 1) * 16;

  half8 kpre0, kpre1, vpre0, vpre1;
  {
    const _Float16* p = Kh + (size_t)(b * 2048 + kkey) * 2048 + h * 128 + kd;
    kpre0 = *(const half8*)p;
    kpre1 = *(const half8*)(p + 8);
    const _Float16* pv = Vt + ((size_t)b << 22) + (size_t)(h * 128 + vd) * 2048 + vkey;
    vpre0 = *(const half8*)pv;
    vpre1 = *(const half8*)(pv + 8);
  }

  float4v o[2][8] = {};
  float4v mrow[2], lrow[2];
#pragma unroll
  for (int rb = 0; rb < 2; rb++)
#pragma unroll
    for (int e = 0; e < 4; e++) { mrow[rb][e] = -INFINITY; lrow[rb][e] = 0.0f; }

  const int nkb = qt * 4 + 4;
  for (int kb = 0; kb < nkb; kb++) {
    const int k0 = kb * 32;
    __syncthreads();
    *(half8*)&Ksh[kkey][kd] = kpre0;
    *(half8*)&Ksh[kkey][kd + 8] = kpre1;
    *(half8*)&Vsh[vd][vkey] = vpre0;
    *(half8*)&Vsh[vd][vkey + 8] = vpre1;
    __syncthreads();

    if (kb + 1 < nkb) {
      const int k1 = k0 + 32;
      const _Float16* p = Kh + (size_t)(b * 2048 + k1 + kkey) * 2048 + h * 128 + kd;
      kpre0 = *(const half8*)p;
      kpre1 = *(const half8*)(p + 8);
      const _Float16* pv = Vt + ((size_t)b << 22) + (size_t)(h * 128 + vd) * 2048 + k1 + vkey;
      vpre0 = *(const half8*)pv;
      vpre1 = *(const half8*)(pv + 8);
    }

    if (k0 <= wq0 + 31) {
      // ---- S = Q K^T ----
      float4v s[2][2] = {};
#pragma unroll
      for (int kc = 0; kc < 4; kc++) {
        half8 kf0 = *(const half8*)&Ksh[l16][kc * 32 + quad * 8];
        half8 kf1 = *(const half8*)&Ksh[16 + l16][kc * 32 + quad * 8];
#pragma unroll
        for (int rb = 0; rb < 2; rb++) {
          s[rb][0] = __builtin_amdgcn_mfma_f32_16x16x32_f16(qf[rb][kc], kf0, s[rb][0], 0, 0, 0);
          s[rb][1] = __builtin_amdgcn_mfma_f32_16x16x32_f16(qf[rb][kc], kf1, s[rb][1], 0, 0, 0);
        }
      }
      // ---- causal mask (diag band only) ----
      if (k0 + 31 > wq0) {
#pragma unroll
        for (int rb = 0; rb < 2; rb++)
#pragma unroll
          for (int cb = 0; cb < 2; cb++)
#pragma unroll
            for (int reg = 0; reg < 4; reg++) {
              const int key = k0 + cb * 16 + l16;
              const int row = wq0 + rb * 16 + quad * 4 + reg;
              if (key > row) s[rb][cb][reg] = -INFINITY;
            }
      }
      // ---- online softmax (exp2 domain) ----
#pragma unroll
      for (int rb = 0; rb < 2; rb++) {
        float4v mt;
#pragma unroll
        for (int e = 0; e < 4; e++) mt[e] = fmaxf(s[rb][0][e], s[rb][1][e]);
#pragma unroll
        for (int msk = 1; msk <= 8; msk <<= 1)
#pragma unroll
          for (int e = 0; e < 4; e++) mt[e] = fmaxf(mt[e], __shfl_xor(mt[e], msk, 64));
        float4v al;
#pragma unroll
        for (int e = 0; e < 4; e++) {
          const float mn = fmaxf(mrow[rb][e], mt[e]);
          al[e] = exp2f(mrow[rb][e] - mn);
          mrow[rb][e] = mn;
        }
        float4v rs;
#pragma unroll
        for (int e = 0; e < 4; e++) {
          s[rb][0][e] = exp2f(s[rb][0][e] - mrow[rb][e]);
          s[rb][1][e] = exp2f(s[rb][1][e] - mrow[rb][e]);
          rs[e] = s[rb][0][e] + s[rb][1][e];
        }
#pragma unroll
        for (int msk = 1; msk <= 8; msk <<= 1)
#pragma unroll
          for (int e = 0; e < 4; e++) rs[e] += __shfl_xor(rs[e], msk, 64);
#pragma unroll
        for (int e = 0; e < 4; e++) lrow[rb][e] = lrow[rb][e] * al[e] + rs[e];
#pragma unroll
        for (int cd = 0; cd < 8; cd++)
#pragma unroll
          for (int e = 0; e < 4; e++) o[rb][cd][e] *= al[e];
        // P -> per-wave LDS (C-layout -> A-layout round trip)
#pragma unroll
        for (int cb = 0; cb < 2; cb++)
#pragma unroll
          for (int reg = 0; reg < 4; reg++)
            Psh[wave][rb * 16 + quad * 4 + reg][cb * 16 + l16] = (_Float16)s[rb][cb][reg];
      }
      // ---- O += P V ----
      half8 pf[2];
#pragma unroll
      for (int rb = 0; rb < 2; rb++)
        pf[rb] = *(const half8*)&Psh[wave][rb * 16 + l16][quad * 8];
#pragma unroll
      for (int cd = 0; cd < 8; cd++) {
        half8 vf = *(const half8*)&Vsh[cd * 16 + l16][quad * 8];
#pragma unroll
        for (int rb = 0; rb < 2; rb++)
          o[rb][cd] = __builtin_amdgcn_mfma_f32_16x16x32_f16(pf[rb], vf, o[rb][cd], 0, 0, 0);
      }
    }
  }

  // ---- finalize: O /= l, write fp16 ----
#pragma unroll
  for (int rb = 0; rb < 2; rb++) {
    float4v inv;
#pragma unroll
    for (int e = 0; e < 4; e++) inv[e] = 1.0f / lrow[rb][e];
#pragma unroll
    for (int cd = 0; cd < 8; cd++)
#pragma unroll
      for (int reg = 0; reg < 4; reg++)
        Oh[(size_t)(b * 2048 + wq0 + rb * 16 + quad * 4 + reg) * 2048 +
           h * 128 + cd * 16 + l16] = (_Float16)(o[rb][cd][reg] * inv[reg]);
  }
}

// ---------------- launcher ----------------------------------------------
extern "C" void kernel_launch(void* const* d_in, const int* in_sizes, int n_in,
                              void* d_out, int out_size, void* d_ws,
                              size_t ws_size, hipStream_t stream) {
  const float* x = (const float*)d_in[0];
  const float* Wq = (const float*)d_in[1];
  const float* Wk = (const float*)d_in[2];
  const float* Wv = (const float*)d_in[3];
  const float* W1 = (const float*)d_in[4];
  const float* b1 = (const float*)d_in[5];
  const float* W2 = (const float*)d_in[6];
  const float* b2 = (const float*)d_in[7];
  float* out = (float*)d_out;

  const int ME = 8388608;  // 4096*2048 (also numel(x))
  const int EE = 4194304;  // 2048*2048

  _Float16* ws = (_Float16*)d_ws;
  _Float16* xh  = ws;                 // 8.4M halves
  _Float16* Wqh = xh + ME;            // 4.2M
  _Float16* Wkh = Wqh + EE;
  _Float16* Wvh = Wkh + EE;
  _Float16* Qh  = Wvh + EE;           // 8.4M
  _Float16* Kh  = Qh + ME;
  _Float16* Vt  = Kh + ME;            // ends at 92.3 MB
  _Float16* Oh  = xh;                 // alias (xh dead after QKV)
  _Float16* W1h = Wqh;                // alias over Wq+Wk (dead after QKV)
  _Float16* W2h = Vt;                 // alias (Vt dead after attention)
  _Float16* Hid = Qh;                 // alias over Qh+Kh (dead after attention)

  const float qscale = 1.4426950408889634f * 0.08838834764831845f;  // log2e/sqrt(128)

  // convert x (and fold qscale into Wq), Wk, Wv
  cvt_kernel<<<dim3(1024, 4), 256, 0, stream>>>(x, Wq, Wk, Wv, xh, Wqh, Wkh, Wvh,
                                                ME, EE, EE, EE, qscale);
  // QKV projections: one launch, z = 0/1/2
  gemm_qkv<<<dim3(16, 32, 3), 256, 0, stream>>>(xh, Wqh, Wkh, Wvh, Qh, Kh, Vt);
  // attention
  attn_mfma<<<dim3(16, 16, 2), 256, 0, stream>>>(Qh, Kh, Vt, Oh);
  // convert FFN weights (regions now dead)
  cvt_kernel<<<dim3(1024, 2), 256, 0, stream>>>(W1, W2, nullptr, nullptr,
                                                W1h, W2h, nullptr, nullptr,
                                                ME, ME, 0, 0, 1.0f);
  // FFN
  gemm_ffn<true><<<dim3(32, 32), 256, 0, stream>>>(Oh, W1h, b1, Hid, 4096, 4096, 2048);
  gemm_ffn<false><<<dim3(16, 32), 256, 0, stream>>>(Hid, W2h, b2, out, 4096, 2048, 4096);
}